// Round 3
// baseline (200.614 us; speedup 1.0000x reference)
//
#include <hip/hip_runtime.h>
#include <hip/hip_bf16.h>

typedef __bf16 bf16x8 __attribute__((ext_vector_type(8)));
typedef float  f32x16 __attribute__((ext_vector_type(16)));
typedef float  f32x4  __attribute__((ext_vector_type(4)));
typedef float  f32x2  __attribute__((ext_vector_type(2)));

static __device__ __forceinline__ f32x16 mfma32(bf16x8 a, bf16x8 b, f32x16 c) {
    return __builtin_amdgcn_mfma_f32_32x32x16_bf16(a, b, c, 0, 0, 0);
}

// gelu-tanh via sigmoid with log2e folded in:
// gelu(h) = h / (1 + exp2(-h*(C1 + C2*h^2)))
#define GELU_C1 2.30220820f
#define GELU_C2 0.10294324f

// gelu+gate on 8 consecutive elements of an accumulator (base = 0 or 8)
static __device__ __forceinline__ bf16x8 gelu8(f32x16 a, int base, float gv) {
    bf16x8 r;
    #pragma unroll
    for (int p = 0; p < 4; ++p) {
        f32x2 hh; hh[0] = a[base + 2 * p]; hh[1] = a[base + 2 * p + 1];
        f32x2 tt = hh * hh;
        f32x2 pp;
        pp[0] = fmaf(tt[0], -GELU_C2, -GELU_C1);
        pp[1] = fmaf(tt[1], -GELU_C2, -GELU_C1);
        f32x2 mm = hh * pp;
        float e0 = __builtin_amdgcn_exp2f(mm[0]);
        float e1 = __builtin_amdgcn_exp2f(mm[1]);
        float q0 = __builtin_amdgcn_rcpf(1.f + e0);
        float q1 = __builtin_amdgcn_rcpf(1.f + e1);
        r[2 * p]     = (__bf16)(hh[0] * q0 * gv);
        r[2 * p + 1] = (__bf16)(hh[1] * q1 * gv);
    }
    return r;
}

// ---------------------------------------------------------------------------
// Pack kernel: W1p (K=128, no bias column), W2p (sigma-permuted), be1p
// (f32 layer-1 bias packed in MFMA D-fragment order), router weights fp64.
// ---------------------------------------------------------------------------
__global__ __launch_bounds__(256) void pack_kernel(
    const float* __restrict__ We1, const float* __restrict__ be1,
    const float* __restrict__ Ws1, const float* __restrict__ bs1,
    const float* __restrict__ We2, const float* __restrict__ Ws2,
    const float* __restrict__ Wr1, const float* __restrict__ br1,
    const float* __restrict__ Wr2, const float* __restrict__ br2,
    __bf16* __restrict__ w1p, __bf16* __restrict__ w2p,
    float* __restrict__ be1p,
    double* __restrict__ wr1d, double* __restrict__ br1d,
    double* __restrict__ wr2d, double* __restrict__ br2d)
{
    int tid = blockIdx.x * 256 + threadIdx.x;
    if (tid < 20480) {
        // W1p: [e][nt][ks][64 lanes][8]; n = nt*32+(l&31), k = ks*16+(l>>5)*8+j
        int l  = tid & 63;
        int ks = (tid >> 6) & 7;
        int nt = (tid >> 9) & 3;
        int e  = tid >> 11;
        const float* src = (e < 8) ? (We1 + e * 16384) : (Ws1 + (e - 8) * 16384);
        int n  = nt * 32 + (l & 31);
        int kb = ks * 16 + (l >> 5) * 8;
        bf16x8 v;
        #pragma unroll
        for (int j = 0; j < 8; ++j) v[j] = (__bf16)src[(kb + j) * 128 + n];
        *(bf16x8*)(w1p + (size_t)tid * 8) = v;
    } else if (tid < 40960) {
        // W2p: sigma-permuted k within each kq group of 16
        int t2 = tid - 20480;
        int l  = t2 & 63;
        int ks = (t2 >> 6) & 7;
        int ot = (t2 / 512) & 3;
        int e  = t2 / 2048;
        const float* src = (e < 8) ? (We2 + e * 16384) : (Ws2 + (e - 8) * 16384);
        int o  = ot * 32 + (l & 31);
        int lh = l >> 5;
        bf16x8 v;
        #pragma unroll
        for (int j = 0; j < 8; ++j) {
            int hid = 16 * ks + 8 * (j >> 2) + 4 * lh + (j & 3);
            v[j] = (__bf16)src[hid * 128 + o];
        }
        *(bf16x8*)(w2p + (size_t)t2 * 8) = v;
    } else if (tid < 42240) {
        // be1p: [e][nt][hi][16 r] with n = 32nt + (r&3)+8*(r>>2)+4*hi (f32 exact)
        int i  = tid - 40960;
        int r  = i & 15;
        int h2 = (i >> 4) & 1;
        int nt = (i >> 5) & 3;
        int e  = i >> 7;
        int n  = 32 * nt + (r & 3) + 8 * (r >> 2) + 4 * h2;
        be1p[i] = (e < 8) ? be1[e * 128 + n] : bs1[(e - 8) * 128 + n];
    } else if (tid < 44288) {
        int i = tid - 42240;            // 0..2047: Wr1 [128][16]
        wr1d[i] = (double)Wr1[i];
    } else if (tid < 44416) {
        int i = tid - 44288;            // 0..127: Wr2 [16][8]
        wr2d[i] = (double)Wr2[i];
    } else if (tid < 44432) {
        int i = tid - 44416;            // 0..15
        br1d[i] = (double)br1[i];
    } else if (tid < 44440) {
        int i = tid - 44432;            // 0..7
        br2d[i] = (double)br2[i];
    }
}

// ---------------------------------------------------------------------------
// Fused MoE kernel v3: fp64 router fused back in (layer-1 reads x from
// global, L1-warm from Xp staging; fp64 scratch overlays the dead Hs LDS),
// K=128 GEMM1 with exact-f32 post-GEMM bias, cross-expert weight prefetch.
// 128 tokens/block, 4 waves = (mp, oh). LDS 68 KB -> 2 blocks/CU.
// ---------------------------------------------------------------------------
__global__ __launch_bounds__(256, 2) void moe_main_kernel(
    const float* __restrict__ x,
    const double* __restrict__ wr1d, const double* __restrict__ br1d,
    const double* __restrict__ wr2d, const double* __restrict__ br2d,
    const __bf16* __restrict__ w1p, const __bf16* __restrict__ w2p,
    const float* __restrict__ be1p,
    const float* __restrict__ be2, const float* __restrict__ bs2,
    float* __restrict__ out)
{
    __shared__ __align__(16) char lds[69632];
    __bf16* Xp  = (__bf16*)lds;               // [4 mt][8 ks][64][8] = 32768 B
    __bf16* Hs  = (__bf16*)(lds + 32768);     // [4 mt][8 kq][64][8] = 32768 B
    float*  mg  = (float*)(lds + 65536);      // [128][8] = 4096 B
    double* rfs = (double*)(lds + 32768);     // router overlay on Hs: [128][17]

    const int t    = threadIdx.x;
    const int lane = t & 63;
    const int wave = t >> 6;
    const int l31  = lane & 31;
    const int hi   = lane >> 5;
    const int mp   = wave >> 1;
    const int oh   = wave & 1;
    const int tok0 = blockIdx.x * 128;

    const bf16x8* w1v = (const bf16x8*)w1p;
    const bf16x8* w2v = (const bf16x8*)w2p;

    // ---- e=0 weight preload: lands during router phase ----
    bf16x8 wb0[8], wb1[8], wB0[8];
    {
        const bf16x8* wp  = w1v + ((size_t)(2 * oh) * 8) * 64 + lane;
        const bf16x8* wBp = w2v + ((size_t)(2 * oh) * 8) * 64 + lane;
        #pragma unroll
        for (int ks = 0; ks < 8; ++ks) {
            wb0[ks] = wp[ks * 64];
            wb1[ks] = wp[(8 + ks) * 64];
            wB0[ks] = wBp[ks * 64];
        }
    }

    // ---- stage X as bf16 B-frags ----
    #pragma unroll
    for (int i = 0; i < 8; ++i) {
        int g = i * 256 + t;       // 8-elem group id, 0..2047
        int m = g >> 4;            // token 0..127
        int c = g & 15;            // 8-k chunk
        const f32x4* sp = (const f32x4*)(x + (size_t)(tok0 + m) * 128 + c * 8);
        f32x4 va = sp[0], vb = sp[1];
        bf16x8 v;
        v[0]=(__bf16)va[0]; v[1]=(__bf16)va[1]; v[2]=(__bf16)va[2]; v[3]=(__bf16)va[3];
        v[4]=(__bf16)vb[0]; v[5]=(__bf16)vb[1]; v[6]=(__bf16)vb[2]; v[7]=(__bf16)vb[3];
        *(bf16x8*)&Xp[(((m >> 5) * 8 + (c >> 1)) * 64 + (c & 1) * 32 + (m & 31)) * 8] = v;
    }

    // ---- router layer 1 (fp64): thread (tok=t>>1, rq8=(t&1)*8) -> 8 rf ----
    {
        const int tok = t >> 1;
        const int rq8 = (t & 1) * 8;
        double rf[8];
        #pragma unroll
        for (int j = 0; j < 8; ++j) rf[j] = br1d[rq8 + j];
        const float* xr = x + (size_t)(tok0 + tok) * 128;
        #pragma unroll 4
        for (int c = 0; c < 64; ++c) {
            f32x2 xv2 = *(const f32x2*)(xr + c * 2);
            #pragma unroll
            for (int q = 0; q < 2; ++q) {
                double xv = (double)xv2[q];
                const double* wrow = wr1d + (c * 2 + q) * 16 + rq8;
                #pragma unroll
                for (int j = 0; j < 8; ++j) rf[j] = fma(xv, wrow[j], rf[j]);
            }
        }
        double* rr = rfs + tok * 17 + rq8;
        #pragma unroll
        for (int j = 0; j < 8; ++j) rr[j] = rf[j] > 0.0 ? rf[j] : 0.0;
    }
    __syncthreads();

    // ---- router layer 2 + softmax + div-free mask (fp64), 1 thr/token ----
    if (t < 128) {
        double lg[8];
        #pragma unroll
        for (int j = 0; j < 8; ++j) lg[j] = br2d[j];
        #pragma unroll
        for (int r = 0; r < 16; ++r) {
            double rv = rfs[t * 17 + r];
            #pragma unroll
            for (int j = 0; j < 8; ++j)
                lg[j] = fma(rv, wr2d[r * 8 + j], lg[j]);
        }
        double mx = lg[0];
        #pragma unroll
        for (int j = 1; j < 8; ++j) mx = lg[j] > mx ? lg[j] : mx;
        double ex[8]; double s = 0.0;
        #pragma unroll
        for (int j = 0; j < 8; ++j) { ex[j] = exp(lg[j] - mx); s += ex[j]; }
        double ms = 0.0;
        bool mk[8];
        #pragma unroll
        for (int j = 0; j < 8; ++j) {
            mk[j] = (8.0 * ex[j] > s);
            ms += mk[j] ? ex[j] : 0.0;
        }
        double inv = 1.0 / (ms + s * 1e-8);
        f32x4 o0, o1;
        #pragma unroll
        for (int j = 0; j < 4; ++j) {
            o0[j] = mk[j]     ? (float)(ex[j] * inv)     : 0.f;
            o1[j] = mk[4 + j] ? (float)(ex[4 + j] * inv) : 0.f;
        }
        *(f32x4*)&mg[t * 8]     = o0;
        *(f32x4*)&mg[t * 8 + 4] = o1;
    }
    __syncthreads();   // mg ready; Hs overlay free from here on

    f32x16 acc00, acc01, acc10, acc11;
    #pragma unroll
    for (int i = 0; i < 16; ++i) { acc00[i]=0.f; acc01[i]=0.f; acc10[i]=0.f; acc11[i]=0.f; }

    #pragma unroll 1
    for (int e = 0; e < 10; ++e) {
        float gv0 = 1.0f, gv1 = 1.0f;
        if (e < 8) {
            gv0 = mg[(64 * mp + l31) * 8 + e];
            gv1 = mg[(64 * mp + 32 + l31) * 8 + e];
        }
        // bias frags for this (e, nt-pair, hi): exact f32, D-fragment order
        const float* bp = be1p + (size_t)((e * 4 + 2 * oh) * 2 + hi) * 16;
        f32x16 bA = *(const f32x16*)bp;
        f32x16 bB = *(const f32x16*)(bp + 32);

        // ---- GEMM1 mi=0 ----
        __builtin_amdgcn_s_setprio(1);
        f32x16 a0, a1;
        #pragma unroll
        for (int i = 0; i < 16; ++i) { a0[i] = 0.f; a1[i] = 0.f; }
        #pragma unroll
        for (int ks = 0; ks < 8; ++ks) {
            bf16x8 xb = *(const bf16x8*)&Xp[(((2 * mp) * 8 + ks) * 64 + lane) * 8];
            a0 = mfma32(wb0[ks], xb, a0);
            a1 = mfma32(wb1[ks], xb, a1);
        }
        __builtin_amdgcn_s_setprio(0);
        a0 += bA; a1 += bB;
        {
            int rb = ((2 * mp) * 8 + 4 * oh) * 64 + lane;
            *(bf16x8*)&Hs[(rb + 0 * 64) * 8] = gelu8(a0, 0, gv0);
            *(bf16x8*)&Hs[(rb + 1 * 64) * 8] = gelu8(a0, 8, gv0);
            *(bf16x8*)&Hs[(rb + 2 * 64) * 8] = gelu8(a1, 0, gv0);
            *(bf16x8*)&Hs[(rb + 3 * 64) * 8] = gelu8(a1, 8, gv0);
        }
        // ---- GEMM1 mi=1 ----
        __builtin_amdgcn_s_setprio(1);
        f32x16 c0, c1;
        #pragma unroll
        for (int i = 0; i < 16; ++i) { c0[i] = 0.f; c1[i] = 0.f; }
        #pragma unroll
        for (int ks = 0; ks < 8; ++ks) {
            bf16x8 xb = *(const bf16x8*)&Xp[(((2 * mp + 1) * 8 + ks) * 64 + lane) * 8];
            c0 = mfma32(wb0[ks], xb, c0);
            c1 = mfma32(wb1[ks], xb, c1);
        }
        __builtin_amdgcn_s_setprio(0);
        // prefetch next-expert W1 (drains at barrier1, covered by gelu)
        if (e < 9) {
            const bf16x8* wp = w1v + ((size_t)((e + 1) * 4 + 2 * oh) * 8) * 64 + lane;
            #pragma unroll
            for (int ks = 0; ks < 8; ++ks) {
                wb0[ks] = wp[ks * 64];
                wb1[ks] = wp[(8 + ks) * 64];
            }
        }
        c0 += bA; c1 += bB;
        {
            int rb = ((2 * mp + 1) * 8 + 4 * oh) * 64 + lane;
            *(bf16x8*)&Hs[(rb + 0 * 64) * 8] = gelu8(c0, 0, gv1);
            *(bf16x8*)&Hs[(rb + 1 * 64) * 8] = gelu8(c0, 8, gv1);
            *(bf16x8*)&Hs[(rb + 2 * 64) * 8] = gelu8(c1, 0, gv1);
            *(bf16x8*)&Hs[(rb + 3 * 64) * 8] = gelu8(c1, 8, gv1);
        }
        __syncthreads();

        // ---- GEMM2: wB1 loaded here, consumed incrementally under MFMAs ----
        bf16x8 wB1[8];
        {
            const bf16x8* wBp = w2v + ((size_t)(e * 4 + 2 * oh) * 8) * 64 + lane;
            #pragma unroll
            for (int kq = 0; kq < 8; ++kq) wB1[kq] = wBp[(8 + kq) * 64];
        }
        __builtin_amdgcn_s_setprio(1);
        #pragma unroll
        for (int kq = 0; kq < 8; ++kq) {
            bf16x8 h0 = *(const bf16x8*)&Hs[(((2 * mp)     * 8 + kq) * 64 + lane) * 8];
            bf16x8 h1 = *(const bf16x8*)&Hs[(((2 * mp + 1) * 8 + kq) * 64 + lane) * 8];
            acc00 = mfma32(h0, wB0[kq], acc00);
            acc01 = mfma32(h0, wB1[kq], acc01);
            acc10 = mfma32(h1, wB0[kq], acc10);
            acc11 = mfma32(h1, wB1[kq], acc11);
        }
        __builtin_amdgcn_s_setprio(0);
        // prefetch next-expert wB0 (drains at barrier2)
        if (e < 9) {
            const bf16x8* wBn = w2v + ((size_t)((e + 1) * 4 + 2 * oh) * 8) * 64 + lane;
            #pragma unroll
            for (int kq = 0; kq < 8; ++kq) wB0[kq] = wBn[kq * 64];
        }
        __syncthreads();
    }

    // ---- epilogue: bias (gate-weighted be2 + summed bs2) + store ----
    {
        float be2c[2][8], bsc[2];
        #pragma unroll
        for (int oti = 0; oti < 2; ++oti) {
            int o = 32 * (2 * oh + oti) + l31;
            bsc[oti] = bs2[o] + bs2[128 + o];
            #pragma unroll
            for (int ee = 0; ee < 8; ++ee) be2c[oti][ee] = be2[ee * 128 + o];
        }
        #pragma unroll
        for (int mi = 0; mi < 2; ++mi) {
            const int mt = 2 * mp + mi;
            const float* mgb = mg + (32 * mt) * 8;
            f32x16 aA = mi ? acc10 : acc00;
            f32x16 aB = mi ? acc11 : acc01;
            #pragma unroll
            for (int r = 0; r < 16; ++r) {
                int mrow = (r & 3) + 8 * (r >> 2) + 4 * hi;
                f32x4 g0 = *(const f32x4*)&mgb[mrow * 8];
                f32x4 g1 = *(const f32x4*)&mgb[mrow * 8 + 4];
                size_t orow = (size_t)(tok0 + 32 * mt + mrow) * 128;
                float b0 = bsc[0], b1 = bsc[1];
                #pragma unroll
                for (int ee = 0; ee < 4; ++ee) {
                    b0 = fmaf(g0[ee], be2c[0][ee], b0);
                    b1 = fmaf(g0[ee], be2c[1][ee], b1);
                }
                #pragma unroll
                for (int ee = 0; ee < 4; ++ee) {
                    b0 = fmaf(g1[ee], be2c[0][4 + ee], b0);
                    b1 = fmaf(g1[ee], be2c[1][4 + ee], b1);
                }
                out[orow + 32 * (2 * oh)     + l31] = aA[r] + b0;
                out[orow + 32 * (2 * oh + 1) + l31] = aB[r] + b1;
            }
        }
    }
}

// ---------------------------------------------------------------------------
extern "C" void kernel_launch(void* const* d_in, const int* in_sizes, int n_in,
                              void* d_out, int out_size, void* d_ws, size_t ws_size,
                              hipStream_t stream)
{
    const float* x   = (const float*)d_in[0];
    const float* Wr1 = (const float*)d_in[1];
    const float* br1 = (const float*)d_in[2];
    const float* Wr2 = (const float*)d_in[3];
    const float* br2 = (const float*)d_in[4];
    const float* We1 = (const float*)d_in[5];
    const float* be1 = (const float*)d_in[6];
    const float* We2 = (const float*)d_in[7];
    const float* be2 = (const float*)d_in[8];
    const float* Ws1 = (const float*)d_in[9];
    const float* bs1 = (const float*)d_in[10];
    const float* Ws2 = (const float*)d_in[11];
    const float* bs2 = (const float*)d_in[12];

    // ws: w1p [0,327680); w2p [327680,655360); be1p [655360,660480);
    // wr1d [660480,676864); wr2d [676864,677888); br1d [677888,678016);
    // br2d [678016,678080)
    __bf16* w1p  = (__bf16*)d_ws;
    __bf16* w2p  = (__bf16*)((char*)d_ws + 327680);
    float*  be1p = (float*)((char*)d_ws + 655360);
    double* wr1d = (double*)((char*)d_ws + 660480);
    double* wr2d = (double*)((char*)d_ws + 676864);
    double* br1d = (double*)((char*)d_ws + 677888);
    double* br2d = (double*)((char*)d_ws + 678016);

    pack_kernel<<<174, 256, 0, stream>>>(We1, be1, Ws1, bs1, We2, Ws2,
                                         Wr1, br1, Wr2, br2,
                                         w1p, w2p, be1p, wr1d, br1d, wr2d, br2d);
    moe_main_kernel<<<512, 256, 0, stream>>>(x, wr1d, br1d, wr2d, br2d,
                                             w1p, w2p, be1p, be2, bs2,
                                             (float*)d_out);
}

// Round 4
// 182.430 us; speedup vs baseline: 1.0997x; 1.0997x over previous
//
#include <hip/hip_runtime.h>
#include <hip/hip_bf16.h>

typedef __bf16 bf16x8 __attribute__((ext_vector_type(8)));
typedef float  f32x16 __attribute__((ext_vector_type(16)));
typedef float  f32x4  __attribute__((ext_vector_type(4)));
typedef float  f32x2  __attribute__((ext_vector_type(2)));

static __device__ __forceinline__ f32x16 mfma32(bf16x8 a, bf16x8 b, f32x16 c) {
    return __builtin_amdgcn_mfma_f32_32x32x16_bf16(a, b, c, 0, 0, 0);
}

// gelu-tanh via sigmoid with log2e folded in:
// gelu(h) = h / (1 + exp2(-h*(C1 + C2*h^2)))
#define GELU_C1 2.30220820f
#define GELU_C2 0.10294324f

// gelu+gate on 8 consecutive elements of an accumulator (base = 0 or 8)
static __device__ __forceinline__ bf16x8 gelu8(f32x16 a, int base, float gv) {
    bf16x8 r;
    #pragma unroll
    for (int p = 0; p < 4; ++p) {
        f32x2 hh; hh[0] = a[base + 2 * p]; hh[1] = a[base + 2 * p + 1];
        f32x2 tt = hh * hh;
        f32x2 pp;
        pp[0] = fmaf(tt[0], -GELU_C2, -GELU_C1);
        pp[1] = fmaf(tt[1], -GELU_C2, -GELU_C1);
        f32x2 mm = hh * pp;
        float e0 = __builtin_amdgcn_exp2f(mm[0]);
        float e1 = __builtin_amdgcn_exp2f(mm[1]);
        float q0 = __builtin_amdgcn_rcpf(1.f + e0);
        float q1 = __builtin_amdgcn_rcpf(1.f + e1);
        r[2 * p]     = (__bf16)(hh[0] * q0 * gv);
        r[2 * p + 1] = (__bf16)(hh[1] * q1 * gv);
    }
    return r;
}

// ---------------------------------------------------------------------------
// Pack kernel: W1p (K=128), W2p (sigma-permuted, [e][kq][ot] order), be1p
// (f32 layer-1 bias in MFMA D-fragment order), router weights fp64.
// ---------------------------------------------------------------------------
__global__ __launch_bounds__(256) void pack_kernel(
    const float* __restrict__ We1, const float* __restrict__ be1,
    const float* __restrict__ Ws1, const float* __restrict__ bs1,
    const float* __restrict__ We2, const float* __restrict__ Ws2,
    const float* __restrict__ Wr1, const float* __restrict__ br1,
    const float* __restrict__ Wr2, const float* __restrict__ br2,
    __bf16* __restrict__ w1p, __bf16* __restrict__ w2p,
    float* __restrict__ be1p,
    double* __restrict__ wr1d, double* __restrict__ br1d,
    double* __restrict__ wr2d, double* __restrict__ br2d)
{
    int tid = blockIdx.x * 256 + threadIdx.x;
    if (tid < 20480) {
        // W1p: [e][nt][ks][64 lanes][8]; n = nt*32+(l&31), k = ks*16+(l>>5)*8+j
        int l  = tid & 63;
        int ks = (tid >> 6) & 7;
        int nt = (tid >> 9) & 3;
        int e  = tid >> 11;
        const float* src = (e < 8) ? (We1 + e * 16384) : (Ws1 + (e - 8) * 16384);
        int n  = nt * 32 + (l & 31);
        int kb = ks * 16 + (l >> 5) * 8;
        bf16x8 v;
        #pragma unroll
        for (int j = 0; j < 8; ++j) v[j] = (__bf16)src[(kb + j) * 128 + n];
        *(bf16x8*)(w1p + (size_t)tid * 8) = v;
    } else if (tid < 40960) {
        // W2p: [e][kq][ot][64 lanes][8]; sigma-permuted k within each kq group
        int t2 = tid - 20480;
        int l  = t2 & 63;
        int ot = (t2 >> 6) & 3;
        int kq = (t2 >> 8) & 7;
        int e  = t2 >> 11;
        const float* src = (e < 8) ? (We2 + e * 16384) : (Ws2 + (e - 8) * 16384);
        int o  = 32 * ot + (l & 31);
        int lh = l >> 5;
        bf16x8 v;
        #pragma unroll
        for (int j = 0; j < 8; ++j) {
            int hid = 16 * kq + 8 * (j >> 2) + 4 * lh + (j & 3);
            v[j] = (__bf16)src[hid * 128 + o];
        }
        *(bf16x8*)(w2p + (size_t)t2 * 8) = v;
    } else if (tid < 42240) {
        // be1p: [e][nt][hi][16 r] with n = 32nt + (r&3)+8*(r>>2)+4*hi (f32 exact)
        int i  = tid - 40960;
        int r  = i & 15;
        int h2 = (i >> 4) & 1;
        int nt = (i >> 5) & 3;
        int e  = i >> 7;
        int n  = 32 * nt + (r & 3) + 8 * (r >> 2) + 4 * h2;
        be1p[i] = (e < 8) ? be1[e * 128 + n] : bs1[(e - 8) * 128 + n];
    } else if (tid < 44288) {
        int i = tid - 42240;            // 0..2047: Wr1 [128][16]
        wr1d[i] = (double)Wr1[i];
    } else if (tid < 44416) {
        int i = tid - 44288;            // 0..127: Wr2 [16][8]
        wr2d[i] = (double)Wr2[i];
    } else if (tid < 44432) {
        int i = tid - 44416;            // 0..15
        br1d[i] = (double)br1[i];
    } else if (tid < 44440) {
        int i = tid - 44432;            // 0..7
        br2d[i] = (double)br2[i];
    }
}

// ---------------------------------------------------------------------------
// Router kernel (fp64, decision-exact) — round-1 version verbatim (the one
// that measured ~17.6 us). Gate decisions bit-identical to all prior rounds.
// ---------------------------------------------------------------------------
__global__ __launch_bounds__(256) void router_kernel(
    const float* __restrict__ x,
    const double* __restrict__ wr1d, const double* __restrict__ br1d,
    const double* __restrict__ wr2d, const double* __restrict__ br2d,
    float* __restrict__ gates)
{
    __shared__ __align__(16) char lds[41472];
    float*  xs  = (float*)lds;                 // 64 rows * 130 f32 = 33280 B
    double* rfs = (double*)(lds + 33280);      // 64*16*8 = 8192 B

    const int t    = threadIdx.x;
    const int tok0 = blockIdx.x * 64;

    // stage x fp32 (stride 130 to dodge bank conflicts)
    #pragma unroll
    for (int i = 0; i < 8; ++i) {
        int cid = i * 256 + t;       // 4-float chunk id, 0..2047
        int m = cid >> 5;            // token 0..63
        int c = cid & 31;            // chunk within row
        f32x4 v = *(const f32x4*)(x + (size_t)(tok0 + m) * 128 + c * 4);
        f32x2 s0, s1;
        s0[0] = v[0]; s0[1] = v[1]; s1[0] = v[2]; s1[1] = v[3];
        *(f32x2*)(xs + m * 130 + c * 4)     = s0;
        *(f32x2*)(xs + m * 130 + c * 4 + 2) = s1;
    }
    __syncthreads();

    // ---- router layer 1 (fp64): thread (tok=t&63, rq=(t>>6)*4) -> 4 rf ----
    {
        const int tok = t & 63;
        const int rq  = (t >> 6) * 4;
        const int rqs = __builtin_amdgcn_readfirstlane(rq);  // force s_loads
        double rf4[4];
        #pragma unroll
        for (int j = 0; j < 4; ++j) rf4[j] = br1d[rqs + j];
        const float* xr = xs + tok * 130;
        #pragma unroll 4
        for (int c = 0; c < 64; ++c) {
            f32x2 xv2 = *(const f32x2*)(xr + c * 2);
            #pragma unroll
            for (int q = 0; q < 2; ++q) {
                double xv = (double)xv2[q];
                int k = c * 2 + q;
                #pragma unroll
                for (int j = 0; j < 4; ++j)
                    rf4[j] = fma(xv, wr1d[k * 16 + rqs + j], rf4[j]);
            }
        }
        #pragma unroll
        for (int j = 0; j < 4; ++j)
            rfs[tok * 16 + rq + j] = rf4[j] > 0.0 ? rf4[j] : 0.0;
    }
    __syncthreads();

    // ---- router layer 2 + softmax + div-free mask (fp64), 1 thr/token ----
    if (t < 64) {
        double lg[8];
        #pragma unroll
        for (int j = 0; j < 8; ++j) lg[j] = br2d[j];
        #pragma unroll
        for (int r = 0; r < 16; ++r) {
            double rv = rfs[t * 16 + r];
            #pragma unroll
            for (int j = 0; j < 8; ++j)
                lg[j] = fma(rv, wr2d[r * 8 + j], lg[j]);
        }
        double mx = lg[0];
        #pragma unroll
        for (int j = 1; j < 8; ++j) mx = lg[j] > mx ? lg[j] : mx;
        double ex[8]; double s = 0.0;
        #pragma unroll
        for (int j = 0; j < 8; ++j) { ex[j] = exp(lg[j] - mx); s += ex[j]; }
        double ms = 0.0;
        bool mk[8];
        #pragma unroll
        for (int j = 0; j < 8; ++j) {
            mk[j] = (8.0 * ex[j] > s);
            ms += mk[j] ? ex[j] : 0.0;
        }
        double inv = 1.0 / (ms + s * 1e-8);
        f32x4 o0, o1;
        #pragma unroll
        for (int j = 0; j < 4; ++j) {
            o0[j] = mk[j]     ? (float)(ex[j] * inv)     : 0.f;
            o1[j] = mk[4 + j] ? (float)(ex[4 + j] * inv) : 0.f;
        }
        *(f32x4*)(gates + (size_t)(tok0 + t) * 8)     = o0;
        *(f32x4*)(gates + (size_t)(tok0 + t) * 8 + 4) = o1;
    }
}

// ---------------------------------------------------------------------------
// Fused expert kernel v4: wave-independent, ZERO LDS, ZERO barriers.
// Each wave owns one 32-token tile (mt = wave) and computes the full expert
// pipeline for it: GEMM1 all 4 nt, gelu in-register (the GEMM1 D-fragment IS
// the GEMM2 A-fragment: hfrag(kq=2nt+b) = gelu8(a(nt), 8b), byte-identical
// to the old Hs LDS path), GEMM2 all 4 ot. X held in 32 VGPRs; W1/W2 stream
// L2->reg with ping-pong prefetch. 64 MFMA/wave/expert.
// ---------------------------------------------------------------------------
#define GEMM2_STEP(W)                                   \
    acc0 = mfma32(h0, W[0], acc0);                      \
    acc1 = mfma32(h0, W[1], acc1);                      \
    acc2 = mfma32(h0, W[2], acc2);                      \
    acc3 = mfma32(h0, W[3], acc3);                      \
    acc0 = mfma32(h1, W[4], acc0);                      \
    acc1 = mfma32(h1, W[5], acc1);                      \
    acc2 = mfma32(h1, W[6], acc2);                      \
    acc3 = mfma32(h1, W[7], acc3);

#define PREF_WB(W, en, ntn)                                                  \
    {                                                                        \
        const bf16x8* bp2 = w2v + ((size_t)((en) * 32 + 8 * (ntn))) * 64 + lane; \
        _Pragma("unroll")                                                    \
        for (int f = 0; f < 8; ++f) W[f] = bp2[f * 64];                      \
    }

__global__ __launch_bounds__(256, 2) void moe_main_kernel(
    const float* __restrict__ x, const float* __restrict__ gates,
    const __bf16* __restrict__ w1p, const __bf16* __restrict__ w2p,
    const float* __restrict__ be1p,
    const float* __restrict__ be2, const float* __restrict__ bs2,
    float* __restrict__ out)
{
    const int t    = threadIdx.x;
    const int lane = t & 63;
    const int mt   = t >> 6;        // this wave's token tile
    const int l31  = lane & 31;
    const int hi   = lane >> 5;
    const int tok0 = blockIdx.x * 128;
    const size_t row = (size_t)(tok0 + 32 * mt + l31);   // this lane's token

    const bf16x8* w1v = (const bf16x8*)w1p;
    const bf16x8* w2v = (const bf16x8*)w2p;

    // ---- initial weight prefetch (e=0, nt=0) ----
    bf16x8 wb[8];
    {
        const bf16x8* wp = w1v + lane;
        #pragma unroll
        for (int ks = 0; ks < 8; ++ks) wb[ks] = wp[ks * 64];
    }
    bf16x8 wBa[8], wBb[8];
    PREF_WB(wBa, 0, 0)

    // ---- X fragments in registers: xf[ks], k = 16ks + 8hi + j ----
    bf16x8 xf[8];
    {
        const float* xr = x + row * 128 + 8 * hi;
        #pragma unroll
        for (int ks = 0; ks < 8; ++ks) {
            f32x4 va = *(const f32x4*)(xr + 16 * ks);
            f32x4 vb = *(const f32x4*)(xr + 16 * ks + 4);
            bf16x8 v;
            v[0]=(__bf16)va[0]; v[1]=(__bf16)va[1]; v[2]=(__bf16)va[2]; v[3]=(__bf16)va[3];
            v[4]=(__bf16)vb[0]; v[5]=(__bf16)vb[1]; v[6]=(__bf16)vb[2]; v[7]=(__bf16)vb[3];
            xf[ks] = v;
        }
    }

    f32x16 acc0, acc1, acc2, acc3;
    #pragma unroll
    for (int i = 0; i < 16; ++i) { acc0[i]=0.f; acc1[i]=0.f; acc2[i]=0.f; acc3[i]=0.f; }

    #pragma unroll 1
    for (int e = 0; e < 10; ++e) {
        float gv = 1.0f;
        if (e < 8) gv = gates[row * 8 + e];

        #pragma unroll
        for (int nt = 0; nt < 4; ++nt) {
            // bias frag (f32 exact, D-fragment order)
            const f32x16 bfr = *(const f32x16*)(be1p + ((e * 4 + nt) * 2 + hi) * 16);

            // ---- GEMM1(nt): 8 MFMA ----
            __builtin_amdgcn_s_setprio(1);
            f32x16 a;
            #pragma unroll
            for (int i = 0; i < 16; ++i) a[i] = 0.f;
            #pragma unroll
            for (int ks = 0; ks < 8; ++ks) a = mfma32(wb[ks], xf[ks], a);
            __builtin_amdgcn_s_setprio(0);

            // prefetch next W1 tile (nt+1, or e+1 nt0)
            {
                int en  = (nt == 3) ? (e < 9 ? e + 1 : 9) : e;
                int ntn = (nt + 1) & 3;
                const bf16x8* wp = w1v + ((size_t)(en * 4 + ntn) * 8) * 64 + lane;
                #pragma unroll
                for (int ks = 0; ks < 8; ++ks) wb[ks] = wp[ks * 64];
            }

            // ---- gelu + gate in-register -> GEMM2 A-frags ----
            a += bfr;
            bf16x8 h0 = gelu8(a, 0, gv);   // kq = 2nt
            bf16x8 h1 = gelu8(a, 8, gv);   // kq = 2nt+1

            // ---- GEMM2 partial: 8 MFMA into 4 persistent accumulators ----
            __builtin_amdgcn_s_setprio(1);
            if ((nt & 1) == 0) { GEMM2_STEP(wBa) } else { GEMM2_STEP(wBb) }
            __builtin_amdgcn_s_setprio(0);

            // prefetch next W2 group into the other buffer
            {
                int en  = (nt == 3) ? (e < 9 ? e + 1 : 9) : e;
                int ntn = (nt + 1) & 3;
                if ((nt & 1) == 0) { PREF_WB(wBb, en, ntn) }
                else               { PREF_WB(wBa, en, ntn) }
            }
        }
    }

    // ---- epilogue: bias (gate-weighted be2 + summed bs2) + store ----
    {
        float be2c[4][8], bsc[4];
        #pragma unroll
        for (int ot = 0; ot < 4; ++ot) {
            int o = 32 * ot + l31;
            bsc[ot] = bs2[o] + bs2[128 + o];
            #pragma unroll
            for (int ee = 0; ee < 8; ++ee) be2c[ot][ee] = be2[ee * 128 + o];
        }
        #pragma unroll
        for (int r = 0; r < 16; ++r) {
            int mrow = (r & 3) + 8 * (r >> 2) + 4 * hi;
            size_t trow = (size_t)(tok0 + 32 * mt + mrow);
            f32x4 g0 = *(const f32x4*)(gates + trow * 8);
            f32x4 g1 = *(const f32x4*)(gates + trow * 8 + 4);
            size_t obase = trow * 128 + l31;
            #pragma unroll
            for (int ot = 0; ot < 4; ++ot) {
                float b = bsc[ot];
                #pragma unroll
                for (int ee = 0; ee < 4; ++ee) b = fmaf(g0[ee], be2c[ot][ee], b);
                #pragma unroll
                for (int ee = 0; ee < 4; ++ee) b = fmaf(g1[ee], be2c[ot][4 + ee], b);
                float av = (ot == 0) ? acc0[r] : (ot == 1) ? acc1[r]
                         : (ot == 2) ? acc2[r] : acc3[r];
                out[obase + 32 * ot] = av + b;
            }
        }
    }
}

// ---------------------------------------------------------------------------
extern "C" void kernel_launch(void* const* d_in, const int* in_sizes, int n_in,
                              void* d_out, int out_size, void* d_ws, size_t ws_size,
                              hipStream_t stream)
{
    const float* x   = (const float*)d_in[0];
    const float* Wr1 = (const float*)d_in[1];
    const float* br1 = (const float*)d_in[2];
    const float* Wr2 = (const float*)d_in[3];
    const float* br2 = (const float*)d_in[4];
    const float* We1 = (const float*)d_in[5];
    const float* be1 = (const float*)d_in[6];
    const float* We2 = (const float*)d_in[7];
    const float* be2 = (const float*)d_in[8];
    const float* Ws1 = (const float*)d_in[9];
    const float* bs1 = (const float*)d_in[10];
    const float* Ws2 = (const float*)d_in[11];
    const float* bs2 = (const float*)d_in[12];

    // ws: w1p [0,327680); w2p [327680,655360); be1p [655360,660480);
    // wr1d [660480,676864); wr2d [676864,677888); br1d [677888,678016);
    // br2d [678016,678080); gates [720896, 720896+2097152)
    __bf16* w1p  = (__bf16*)d_ws;
    __bf16* w2p  = (__bf16*)((char*)d_ws + 327680);
    float*  be1p = (float*)((char*)d_ws + 655360);
    double* wr1d = (double*)((char*)d_ws + 660480);
    double* wr2d = (double*)((char*)d_ws + 676864);
    double* br1d = (double*)((char*)d_ws + 677888);
    double* br2d = (double*)((char*)d_ws + 678016);
    float*  gts  = (float*)((char*)d_ws + 720896);

    pack_kernel<<<174, 256, 0, stream>>>(We1, be1, Ws1, bs1, We2, Ws2,
                                         Wr1, br1, Wr2, br2,
                                         w1p, w2p, be1p, wr1d, br1d, wr2d, br2d);
    router_kernel<<<1024, 256, 0, stream>>>(x, wr1d, br1d, wr2d, br2d, gts);
    moe_main_kernel<<<512, 256, 0, stream>>>(x, gts, w1p, w2p, be1p, be2, bs2,
                                             (float*)d_out);
}

// Round 5
// 179.915 us; speedup vs baseline: 1.1150x; 1.0140x over previous
//
#include <hip/hip_runtime.h>
#include <hip/hip_bf16.h>

typedef __bf16 bf16x8 __attribute__((ext_vector_type(8)));
typedef float  f32x16 __attribute__((ext_vector_type(16)));
typedef float  f32x4  __attribute__((ext_vector_type(4)));
typedef float  f32x2  __attribute__((ext_vector_type(2)));

static __device__ __forceinline__ f32x16 mfma32(bf16x8 a, bf16x8 b, f32x16 c) {
    return __builtin_amdgcn_mfma_f32_32x32x16_bf16(a, b, c, 0, 0, 0);
}

// async global->LDS, 16B per lane; LDS dest = wave-uniform base + lane*16 (HW)
static __device__ __forceinline__ void gl_lds16(const void* g, void* l) {
    __builtin_amdgcn_global_load_lds(
        (const __attribute__((address_space(1))) unsigned int*)g,
        (__attribute__((address_space(3))) unsigned int*)l,
        16, 0, 0);
}

// gelu-tanh via sigmoid with log2e folded in:
// gelu(h) = h / (1 + exp2(-h*(C1 + C2*h^2)))
#define GELU_C1 2.30220820f
#define GELU_C2 0.10294324f

// gelu+gate on 8 consecutive elements of an accumulator (base = 0 or 8)
static __device__ __forceinline__ bf16x8 gelu8(f32x16 a, int base, float gv) {
    bf16x8 r;
    #pragma unroll
    for (int p = 0; p < 4; ++p) {
        f32x2 hh; hh[0] = a[base + 2 * p]; hh[1] = a[base + 2 * p + 1];
        f32x2 tt = hh * hh;
        f32x2 pp;
        pp[0] = fmaf(tt[0], -GELU_C2, -GELU_C1);
        pp[1] = fmaf(tt[1], -GELU_C2, -GELU_C1);
        f32x2 mm = hh * pp;
        float e0 = __builtin_amdgcn_exp2f(mm[0]);
        float e1 = __builtin_amdgcn_exp2f(mm[1]);
        float q0 = __builtin_amdgcn_rcpf(1.f + e0);
        float q1 = __builtin_amdgcn_rcpf(1.f + e1);
        r[2 * p]     = (__bf16)(hh[0] * q0 * gv);
        r[2 * p + 1] = (__bf16)(hh[1] * q1 * gv);
    }
    return r;
}

// ---------------------------------------------------------------------------
// Pack kernel: W1p (K=128), W2p (sigma-permuted, [e][kq][ot] order), be1p
// (f32 layer-1 bias in MFMA D-fragment order), router weights fp64.
// ---------------------------------------------------------------------------
__global__ __launch_bounds__(256) void pack_kernel(
    const float* __restrict__ We1, const float* __restrict__ be1,
    const float* __restrict__ Ws1, const float* __restrict__ bs1,
    const float* __restrict__ We2, const float* __restrict__ Ws2,
    const float* __restrict__ Wr1, const float* __restrict__ br1,
    const float* __restrict__ Wr2, const float* __restrict__ br2,
    __bf16* __restrict__ w1p, __bf16* __restrict__ w2p,
    float* __restrict__ be1p,
    double* __restrict__ wr1d, double* __restrict__ br1d,
    double* __restrict__ wr2d, double* __restrict__ br2d)
{
    int tid = blockIdx.x * 256 + threadIdx.x;
    if (tid < 20480) {
        // W1p: [e][nt][ks][64 lanes][8]; n = nt*32+(l&31), k = ks*16+(l>>5)*8+j
        int l  = tid & 63;
        int ks = (tid >> 6) & 7;
        int nt = (tid >> 9) & 3;
        int e  = tid >> 11;
        const float* src = (e < 8) ? (We1 + e * 16384) : (Ws1 + (e - 8) * 16384);
        int n  = nt * 32 + (l & 31);
        int kb = ks * 16 + (l >> 5) * 8;
        bf16x8 v;
        #pragma unroll
        for (int j = 0; j < 8; ++j) v[j] = (__bf16)src[(kb + j) * 128 + n];
        *(bf16x8*)(w1p + (size_t)tid * 8) = v;
    } else if (tid < 40960) {
        // W2p: [e][kq][ot][64 lanes][8]; sigma-permuted k within each kq group
        int t2 = tid - 20480;
        int l  = t2 & 63;
        int ot = (t2 >> 6) & 3;
        int kq = (t2 >> 8) & 7;
        int e  = t2 >> 11;
        const float* src = (e < 8) ? (We2 + e * 16384) : (Ws2 + (e - 8) * 16384);
        int o  = 32 * ot + (l & 31);
        int lh = l >> 5;
        bf16x8 v;
        #pragma unroll
        for (int j = 0; j < 8; ++j) {
            int hid = 16 * kq + 8 * (j >> 2) + 4 * lh + (j & 3);
            v[j] = (__bf16)src[hid * 128 + o];
        }
        *(bf16x8*)(w2p + (size_t)t2 * 8) = v;
    } else if (tid < 42240) {
        // be1p: [e][nt][hi][16 r] with n = 32nt + (r&3)+8*(r>>2)+4*hi (f32 exact)
        int i  = tid - 40960;
        int r  = i & 15;
        int h2 = (i >> 4) & 1;
        int nt = (i >> 5) & 3;
        int e  = i >> 7;
        int n  = 32 * nt + (r & 3) + 8 * (r >> 2) + 4 * h2;
        be1p[i] = (e < 8) ? be1[e * 128 + n] : bs1[(e - 8) * 128 + n];
    } else if (tid < 44288) {
        int i = tid - 42240;            // 0..2047: Wr1 [128][16]
        wr1d[i] = (double)Wr1[i];
    } else if (tid < 44416) {
        int i = tid - 44288;            // 0..127: Wr2 [16][8]
        wr2d[i] = (double)Wr2[i];
    } else if (tid < 44432) {
        int i = tid - 44416;            // 0..15
        br1d[i] = (double)br1[i];
    } else if (tid < 44440) {
        int i = tid - 44432;            // 0..7
        br2d[i] = (double)br2[i];
    }
}

// ---------------------------------------------------------------------------
// Router kernel (fp64, decision-exact) — round-1 version verbatim (~17.6 us).
// Gate decisions bit-identical to all prior rounds.
// ---------------------------------------------------------------------------
__global__ __launch_bounds__(256) void router_kernel(
    const float* __restrict__ x,
    const double* __restrict__ wr1d, const double* __restrict__ br1d,
    const double* __restrict__ wr2d, const double* __restrict__ br2d,
    float* __restrict__ gates)
{
    __shared__ __align__(16) char lds[41472];
    float*  xs  = (float*)lds;                 // 64 rows * 130 f32 = 33280 B
    double* rfs = (double*)(lds + 33280);      // 64*16*8 = 8192 B

    const int t    = threadIdx.x;
    const int tok0 = blockIdx.x * 64;

    // stage x fp32 (stride 130 to dodge bank conflicts)
    #pragma unroll
    for (int i = 0; i < 8; ++i) {
        int cid = i * 256 + t;       // 4-float chunk id, 0..2047
        int m = cid >> 5;            // token 0..63
        int c = cid & 31;            // chunk within row
        f32x4 v = *(const f32x4*)(x + (size_t)(tok0 + m) * 128 + c * 4);
        f32x2 s0, s1;
        s0[0] = v[0]; s0[1] = v[1]; s1[0] = v[2]; s1[1] = v[3];
        *(f32x2*)(xs + m * 130 + c * 4)     = s0;
        *(f32x2*)(xs + m * 130 + c * 4 + 2) = s1;
    }
    __syncthreads();

    // ---- router layer 1 (fp64): thread (tok=t&63, rq=(t>>6)*4) -> 4 rf ----
    {
        const int tok = t & 63;
        const int rq  = (t >> 6) * 4;
        const int rqs = __builtin_amdgcn_readfirstlane(rq);  // force s_loads
        double rf4[4];
        #pragma unroll
        for (int j = 0; j < 4; ++j) rf4[j] = br1d[rqs + j];
        const float* xr = xs + tok * 130;
        #pragma unroll 4
        for (int c = 0; c < 64; ++c) {
            f32x2 xv2 = *(const f32x2*)(xr + c * 2);
            #pragma unroll
            for (int q = 0; q < 2; ++q) {
                double xv = (double)xv2[q];
                int k = c * 2 + q;
                #pragma unroll
                for (int j = 0; j < 4; ++j)
                    rf4[j] = fma(xv, wr1d[k * 16 + rqs + j], rf4[j]);
            }
        }
        #pragma unroll
        for (int j = 0; j < 4; ++j)
            rfs[tok * 16 + rq + j] = rf4[j] > 0.0 ? rf4[j] : 0.0;
    }
    __syncthreads();

    // ---- router layer 2 + softmax + div-free mask (fp64), 1 thr/token ----
    if (t < 64) {
        double lg[8];
        #pragma unroll
        for (int j = 0; j < 8; ++j) lg[j] = br2d[j];
        #pragma unroll
        for (int r = 0; r < 16; ++r) {
            double rv = rfs[t * 16 + r];
            #pragma unroll
            for (int j = 0; j < 8; ++j)
                lg[j] = fma(rv, wr2d[r * 8 + j], lg[j]);
        }
        double mx = lg[0];
        #pragma unroll
        for (int j = 1; j < 8; ++j) mx = lg[j] > mx ? lg[j] : mx;
        double ex[8]; double s = 0.0;
        #pragma unroll
        for (int j = 0; j < 8; ++j) { ex[j] = exp(lg[j] - mx); s += ex[j]; }
        double ms = 0.0;
        bool mk[8];
        #pragma unroll
        for (int j = 0; j < 8; ++j) {
            mk[j] = (8.0 * ex[j] > s);
            ms += mk[j] ? ex[j] : 0.0;
        }
        double inv = 1.0 / (ms + s * 1e-8);
        f32x4 o0, o1;
        #pragma unroll
        for (int j = 0; j < 4; ++j) {
            o0[j] = mk[j]     ? (float)(ex[j] * inv)     : 0.f;
            o1[j] = mk[4 + j] ? (float)(ex[4 + j] * inv) : 0.f;
        }
        *(f32x4*)(gates + (size_t)(tok0 + t) * 8)     = o0;
        *(f32x4*)(gates + (size_t)(tok0 + t) * 8 + 4) = o1;
    }
}

// ---------------------------------------------------------------------------
// Fused expert kernel v5: LDS weight broadcast. One 512-thread block per CU
// (grid 256, LDS 128 KB -> exclusive residency). 8 waves, each owns one
// 32-token tile; compute body is r4's in-register GEMM1 -> gelu -> GEMM2
// (bit-identical math), with weight fragments ds_read from LDS.
// Weights double-buffered at full-expert granularity (2 x 64 KB): fill e+1
// via 8x global_load_lds (16B) per wave while computing e; one
// vmcnt(0) + s_barrier per expert at loop bottom (fill has the whole expert
// phase to land -> drain is free). Per-CU weight delivery: 64 KB/expert via
// LDS pipe (128 B/cyc) instead of 512 KB/expert via L1 (64 B/cyc).
// ---------------------------------------------------------------------------
#define GEMM2_STEP(W)                                   \
    acc0 = mfma32(h0, W[0], acc0);                      \
    acc1 = mfma32(h0, W[1], acc1);                      \
    acc2 = mfma32(h0, W[2], acc2);                      \
    acc3 = mfma32(h0, W[3], acc3);                      \
    acc0 = mfma32(h1, W[4], acc0);                      \
    acc1 = mfma32(h1, W[5], acc1);                      \
    acc2 = mfma32(h1, W[6], acc2);                      \
    acc3 = mfma32(h1, W[7], acc3);

__global__ __launch_bounds__(512, 2) void moe_main_kernel(
    const float* __restrict__ x, const float* __restrict__ gates,
    const __bf16* __restrict__ w1p, const __bf16* __restrict__ w2p,
    const float* __restrict__ be1p,
    const float* __restrict__ be2, const float* __restrict__ bs2,
    float* __restrict__ out)
{
    __shared__ __align__(16) char lds[131072];   // 2 x {W1 32KB | W2 32KB}

    const int t    = threadIdx.x;
    const int lane = t & 63;
    const int wv   = t >> 6;        // wave id 0..7 = this wave's token tile
    const int l31  = lane & 31;
    const int hi   = lane >> 5;
    const int tok0 = blockIdx.x * 256;
    const size_t row = (size_t)(tok0 + 32 * wv + l31);   // this lane's token

    // ---- cooperative expert fill: wave wv copies 4KB slices of W1 and W2 ----
    // (LDS dest uniform per wave; HW adds lane*16. Linear copy: LDS layout ==
    //  global layout: W1 [nt][ks][64][8], W2 [kq][ot][64][8].)
    #define FILL_EXPERT(buf, e)                                                 \
    {                                                                           \
        const char* g1 = (const char*)(w1p + (size_t)(e) * 16384)               \
                         + wv * 4096 + lane * 16;                               \
        const char* g2 = (const char*)(w2p + (size_t)(e) * 16384)               \
                         + wv * 4096 + lane * 16;                               \
        char* l1 = lds + (buf) * 65536 + wv * 4096;                             \
        char* l2 = lds + (buf) * 65536 + 32768 + wv * 4096;                     \
        _Pragma("unroll")                                                       \
        for (int i = 0; i < 4; ++i) {                                           \
            gl_lds16(g1 + i * 1024, l1 + i * 1024);                             \
            gl_lds16(g2 + i * 1024, l2 + i * 1024);                             \
        }                                                                       \
    }

    // prologue: fill buffer 0 with expert 0
    FILL_EXPERT(0, 0)

    // ---- X fragments in registers: xf[ks], k = 16ks + 8hi + j ----
    bf16x8 xf[8];
    {
        const float* xr = x + row * 128 + 8 * hi;
        #pragma unroll
        for (int ks = 0; ks < 8; ++ks) {
            f32x4 va = *(const f32x4*)(xr + 16 * ks);
            f32x4 vb = *(const f32x4*)(xr + 16 * ks + 4);
            bf16x8 v;
            v[0]=(__bf16)va[0]; v[1]=(__bf16)va[1]; v[2]=(__bf16)va[2]; v[3]=(__bf16)va[3];
            v[4]=(__bf16)vb[0]; v[5]=(__bf16)vb[1]; v[6]=(__bf16)vb[2]; v[7]=(__bf16)vb[3];
            xf[ks] = v;
        }
    }

    f32x16 acc0, acc1, acc2, acc3;
    #pragma unroll
    for (int i = 0; i < 16; ++i) { acc0[i]=0.f; acc1[i]=0.f; acc2[i]=0.f; acc3[i]=0.f; }

    // prologue drain: expert-0 fill (and xf loads) complete, all waves synced
    asm volatile("s_waitcnt vmcnt(0)" ::: "memory");
    __builtin_amdgcn_s_barrier();
    __builtin_amdgcn_sched_barrier(0);

    int cur = 0;
    #pragma unroll 1
    for (int e = 0; e < 10; ++e) {
        // issue next expert's fill into the other buffer (overlaps compute)
        if (e < 9) FILL_EXPERT(cur ^ 1, e + 1)

        const bf16x8* W1L = (const bf16x8*)(lds + cur * 65536);
        const bf16x8* W2L = (const bf16x8*)(lds + cur * 65536 + 32768);

        float gv = 1.0f;
        if (e < 8) gv = gates[row * 8 + e];

        #pragma unroll
        for (int nt = 0; nt < 4; ++nt) {
            // W1 frags from LDS (contiguous 1KB per wave-read: conflict-free)
            bf16x8 wb[8];
            #pragma unroll
            for (int ks = 0; ks < 8; ++ks) wb[ks] = W1L[(nt * 8 + ks) * 64 + lane];

            // bias frag (f32 exact, D-fragment order)
            const f32x16 bfr = *(const f32x16*)(be1p + ((e * 4 + nt) * 2 + hi) * 16);

            // ---- GEMM1(nt): 8 MFMA (serial chain, order identical to r4) ----
            __builtin_amdgcn_s_setprio(1);
            f32x16 a;
            #pragma unroll
            for (int i = 0; i < 16; ++i) a[i] = 0.f;
            #pragma unroll
            for (int ks = 0; ks < 8; ++ks) a = mfma32(wb[ks], xf[ks], a);
            __builtin_amdgcn_s_setprio(0);

            // ---- gelu + gate in-register -> GEMM2 A-frags ----
            a += bfr;
            bf16x8 h0 = gelu8(a, 0, gv);   // kq = 2nt
            bf16x8 h1 = gelu8(a, 8, gv);   // kq = 2nt+1

            // W2 frags from LDS: index (kq*4+ot), f = 0..7 -> (2nt*4 + f)
            bf16x8 wB[8];
            #pragma unroll
            for (int f = 0; f < 8; ++f) wB[f] = W2L[(2 * nt * 4 + f) * 64 + lane];

            // ---- GEMM2 partial: 8 MFMA into 4 persistent accumulators ----
            __builtin_amdgcn_s_setprio(1);
            GEMM2_STEP(wB)
            __builtin_amdgcn_s_setprio(0);
        }

        // expert boundary: my fills done (they had the whole phase to land),
        // all waves past their reads of buffer cur -> safe to refill next iter
        asm volatile("s_waitcnt vmcnt(0)" ::: "memory");
        __builtin_amdgcn_s_barrier();
        __builtin_amdgcn_sched_barrier(0);
        cur ^= 1;
    }

    // ---- epilogue: bias (gate-weighted be2 + summed bs2) + store ----
    {
        float be2c[4][8], bsc[4];
        #pragma unroll
        for (int ot = 0; ot < 4; ++ot) {
            int o = 32 * ot + l31;
            bsc[ot] = bs2[o] + bs2[128 + o];
            #pragma unroll
            for (int ee = 0; ee < 8; ++ee) be2c[ot][ee] = be2[ee * 128 + o];
        }
        #pragma unroll
        for (int r = 0; r < 16; ++r) {
            int mrow = (r & 3) + 8 * (r >> 2) + 4 * hi;
            size_t trow = (size_t)(tok0 + 32 * wv + mrow);
            f32x4 g0 = *(const f32x4*)(gates + trow * 8);
            f32x4 g1 = *(const f32x4*)(gates + trow * 8 + 4);
            size_t obase = trow * 128 + l31;
            #pragma unroll
            for (int ot = 0; ot < 4; ++ot) {
                float b = bsc[ot];
                #pragma unroll
                for (int ee = 0; ee < 4; ++ee) b = fmaf(g0[ee], be2c[ot][ee], b);
                #pragma unroll
                for (int ee = 0; ee < 4; ++ee) b = fmaf(g1[ee], be2c[ot][4 + ee], b);
                float av = (ot == 0) ? acc0[r] : (ot == 1) ? acc1[r]
                         : (ot == 2) ? acc2[r] : acc3[r];
                out[obase + 32 * ot] = av + b;
            }
        }
    }
    #undef FILL_EXPERT
}

// ---------------------------------------------------------------------------
extern "C" void kernel_launch(void* const* d_in, const int* in_sizes, int n_in,
                              void* d_out, int out_size, void* d_ws, size_t ws_size,
                              hipStream_t stream)
{
    const float* x   = (const float*)d_in[0];
    const float* Wr1 = (const float*)d_in[1];
    const float* br1 = (const float*)d_in[2];
    const float* Wr2 = (const float*)d_in[3];
    const float* br2 = (const float*)d_in[4];
    const float* We1 = (const float*)d_in[5];
    const float* be1 = (const float*)d_in[6];
    const float* We2 = (const float*)d_in[7];
    const float* be2 = (const float*)d_in[8];
    const float* Ws1 = (const float*)d_in[9];
    const float* bs1 = (const float*)d_in[10];
    const float* Ws2 = (const float*)d_in[11];
    const float* bs2 = (const float*)d_in[12];

    // ws: w1p [0,327680); w2p [327680,655360); be1p [655360,660480);
    // wr1d [660480,676864); wr2d [676864,677888); br1d [677888,678016);
    // br2d [678016,678080); gates [720896, 720896+2097152)
    __bf16* w1p  = (__bf16*)d_ws;
    __bf16* w2p  = (__bf16*)((char*)d_ws + 327680);
    float*  be1p = (float*)((char*)d_ws + 655360);
    double* wr1d = (double*)((char*)d_ws + 660480);
    double* wr2d = (double*)((char*)d_ws + 676864);
    double* br1d = (double*)((char*)d_ws + 677888);
    double* br2d = (double*)((char*)d_ws + 678016);
    float*  gts  = (float*)((char*)d_ws + 720896);

    pack_kernel<<<174, 256, 0, stream>>>(We1, be1, Ws1, bs1, We2, Ws2,
                                         Wr1, br1, Wr2, br2,
                                         w1p, w2p, be1p, wr1d, br1d, wr2d, br2d);
    router_kernel<<<1024, 256, 0, stream>>>(x, wr1d, br1d, wr2d, br2d, gts);
    moe_main_kernel<<<256, 512, 0, stream>>>(x, gts, w1p, w2p, be1p, be2, bs2,
                                             (float*)d_out);
}